// Round 2
// baseline (1267.968 us; speedup 1.0000x reference)
//
#include <hip/hip_runtime.h>
#include <stdint.h>

#define BATCH 8192
#define H1 28
#define W1 28
#define C1 16
#define P1 14
#define C2 32
#define P2 7

#define NPIX1  (BATCH*H1*W1)    // 6,422,528 = 25088*256
#define NPOOL1 (BATCH*P1*P1)    // 1,605,632 = 6272*256
#define NPOOL2 (BATCH*P2*P2)    // 401,408   = 1568*256

#define NBLK1 25088
#define NBLK2 6272

// ---------------------------------------------------------------------------
// Weight prep: binarize weights into compute-friendly tables.
//   w1f : float ±1, [16][25]
//   w2b : 16-bit channel masks, bit ci = (w>=0), [32][25]
//   fcp : packed bytes 0x01 / 0xFF, [10][392] dwords (1568 bytes per row)
// ---------------------------------------------------------------------------
__global__ __launch_bounds__(256) void k_prep(const float* __restrict__ w1,
                                              const float* __restrict__ w2,
                                              const float* __restrict__ fcw,
                                              float* __restrict__ w1f,
                                              unsigned short* __restrict__ w2b,
                                              unsigned* __restrict__ fcp) {
    for (int i = threadIdx.x; i < 400; i += blockDim.x)
        w1f[i] = (w1[i] >= 0.f) ? 1.f : -1.f;
    for (int i = threadIdx.x; i < 800; i += blockDim.x) {
        int co = i / 25, kk = i % 25;
        unsigned m = 0;
        for (int ci = 0; ci < 16; ++ci)
            if (w2[co*400 + ci*25 + kk] >= 0.f) m |= 1u << ci;
        w2b[i] = (unsigned short)m;
    }
    for (int i = threadIdx.x; i < 3920; i += blockDim.x) {
        int j = i / 392, g = i % 392;
        unsigned v = 0;
        for (int by = 0; by < 4; ++by) {
            int k = g*4 + by;
            unsigned char s = (fcw[j*1568 + k] >= 0.f) ? 0x01 : 0xFF;
            v |= ((unsigned)s) << (8*by);
        }
        fcp[i] = v;
    }
}

// ---------------------------------------------------------------------------
// Pass 1a: conv1 in f32 (emulating the reference's f32 rounding: products
// are exact since w=±1, so fma == mul+add == sequential f32 adds in tap
// order) + bias in f32, then per-channel sum/sumsq partials in f64.
// thread = one output pixel (b,oy,ox); computes all 16 channels
// ---------------------------------------------------------------------------
__global__ __launch_bounds__(256) void k_conv1_stats(const float* __restrict__ x,
                                                     const float* __restrict__ w1f,
                                                     const float* __restrict__ b1,
                                                     double* __restrict__ partial1) {
    int t = blockIdx.x*256 + threadIdx.x;
    int b = t / (H1*W1);
    int r = t % (H1*W1);
    int oy = r / W1, ox = r % W1;
    const float* xb = x + (size_t)b * (H1*W1);

    float xd[25];
#pragma unroll
    for (int ky = 0; ky < 5; ++ky) {
        int iy = oy + ky - 2;
#pragma unroll
        for (int kx = 0; kx < 5; ++kx) {
            int ix = ox + kx - 2;
            xd[ky*5 + kx] = (iy >= 0 && iy < H1 && ix >= 0 && ix < W1) ? xb[iy*W1 + ix] : 0.f;
        }
    }

    __shared__ double lsum[4][C1], lsq[4][C1];
    int wave = threadIdx.x >> 6, lane = threadIdx.x & 63;

#pragma unroll 1
    for (int c = 0; c < C1; ++c) {
        float y = 0.f;
#pragma unroll
        for (int i = 0; i < 25; ++i) y = fmaf(w1f[c*25 + i], xd[i], y);
        y = y + b1[c];
        double yd = (double)y;
        double s = yd, q = yd*yd;
#pragma unroll
        for (int off = 32; off; off >>= 1) {
            s += __shfl_down(s, off);
            q += __shfl_down(q, off);
        }
        if (lane == 0) { lsum[wave][c] = s; lsq[wave][c] = q; }
    }
    __syncthreads();
    if (threadIdx.x < C1) {
        int c = threadIdx.x;
        partial1[(size_t)blockIdx.x*32 + c] =
            lsum[0][c] + lsum[1][c] + lsum[2][c] + lsum[3][c];
    } else if (threadIdx.x < 2*C1) {
        int c = threadIdx.x - C1;
        partial1[(size_t)blockIdx.x*32 + 16 + c] =
            lsq[0][c] + lsq[1][c] + lsq[2][c] + lsq[3][c];
    }
}

// ---------------------------------------------------------------------------
// finalize1: reduce partials, compute per-channel threshold + mode
// mode 0: s>0 (take if max >= thr); 1: s<0 (take if min <= thr); 2: +1; 3: -1
// ---------------------------------------------------------------------------
__global__ __launch_bounds__(256) void k_finalize1(const double* __restrict__ part,
                                                   const float* __restrict__ g,
                                                   const float* __restrict__ be,
                                                   double* __restrict__ thr,
                                                   int* __restrict__ mode) {
    int c = blockIdx.x;
    double s = 0, q = 0;
    for (int i = threadIdx.x; i < NBLK1; i += 256) {
        s += part[(size_t)i*32 + c];
        q += part[(size_t)i*32 + 16 + c];
    }
    __shared__ double ls[256], lq[256];
    ls[threadIdx.x] = s; lq[threadIdx.x] = q;
    __syncthreads();
    for (int st = 128; st > 0; st >>= 1) {
        if (threadIdx.x < st) {
            ls[threadIdx.x] += ls[threadIdx.x + st];
            lq[threadIdx.x] += lq[threadIdx.x + st];
        }
        __syncthreads();
    }
    if (threadIdx.x == 0) {
        double N = (double)NPIX1;
        double m = ls[0] / N;
        double var = lq[0] / N - m*m;
        double gamma = (double)g[c], beta = (double)be[c];
        double sc = gamma / sqrt(var + 1e-5);
        int md; double tt = 0.0;
        if (sc > 0)      { md = 0; tt = m - beta / sc; }
        else if (sc < 0) { md = 1; tt = m - beta / sc; }
        else             { md = (beta >= 0) ? 2 : 3; }
        thr[c] = tt; mode[c] = md;
    }
}

// ---------------------------------------------------------------------------
// Pass 1b: recompute conv1 (f32, bitwise-identical op order to pass 1a),
// 2x2 maxpool, sign -> 16-bit channel mask.
// thread = one pooled position (b,py,px)
// ---------------------------------------------------------------------------
__global__ __launch_bounds__(256) void k_a1(const float* __restrict__ x,
                                            const float* __restrict__ w1f,
                                            const float* __restrict__ b1,
                                            const double* __restrict__ thr,
                                            const int* __restrict__ mode,
                                            unsigned short* __restrict__ a1b) {
    int t = blockIdx.x*256 + threadIdx.x;
    int b = t / (P1*P1);
    int r = t % (P1*P1);
    int py = r / P1, px = r % P1;
    const float* xb = x + (size_t)b * (H1*W1);

    float xd[36];
#pragma unroll
    for (int dy = 0; dy < 6; ++dy) {
        int iy = 2*py + dy - 2;
#pragma unroll
        for (int dx = 0; dx < 6; ++dx) {
            int ix = 2*px + dx - 2;
            xd[dy*6 + dx] = (iy >= 0 && iy < H1 && ix >= 0 && ix < W1) ? xb[iy*W1 + ix] : 0.f;
        }
    }

    unsigned maskbits = 0;
#pragma unroll 1
    for (int c = 0; c < C1; ++c) {
        float y0 = 0.f, y1 = 0.f, y2 = 0.f, y3 = 0.f;
#pragma unroll
        for (int ky = 0; ky < 5; ++ky)
#pragma unroll
            for (int kx = 0; kx < 5; ++kx) {
                float w = w1f[c*25 + ky*5 + kx];
                y0 = fmaf(w, xd[ ky   *6 + kx    ], y0);
                y1 = fmaf(w, xd[ ky   *6 + kx + 1], y1);
                y2 = fmaf(w, xd[(ky+1)*6 + kx    ], y2);
                y3 = fmaf(w, xd[(ky+1)*6 + kx + 1], y3);
            }
        float bb = b1[c];
        y0 = y0 + bb; y1 = y1 + bb; y2 = y2 + bb; y3 = y3 + bb;
        float mx = fmaxf(fmaxf(y0, y1), fmaxf(y2, y3));
        float mn = fminf(fminf(y0, y1), fminf(y2, y3));
        int md = mode[c]; double tt = thr[c];
        bool plus = (md == 0) ? ((double)mx >= tt)
                  : (md == 1) ? ((double)mn <= tt)
                  : (md == 2);
        maskbits |= (plus ? 1u : 0u) << c;
    }
    a1b[t] = (unsigned short)maskbits;
}

// ---------------------------------------------------------------------------
// Pass 2a: conv2 via XNOR-popcount (exact ints) + bias in f32
// (fl32(int + b2), exactly what any f32 reference computes), stats in f64.
// thread = one spatial position (b,oy,ox); computes all 32 channels
// ---------------------------------------------------------------------------
__global__ __launch_bounds__(256) void k_conv2_stats(const unsigned short* __restrict__ a1b,
                                                     const unsigned short* __restrict__ w2b,
                                                     const float* __restrict__ b2,
                                                     double* __restrict__ partial2) {
    __shared__ unsigned short sw[800];
    __shared__ float sb[32];
    for (int i = threadIdx.x; i < 800; i += 256) sw[i] = w2b[i];
    if (threadIdx.x < 32) sb[threadIdx.x] = b2[threadIdx.x];
    __syncthreads();

    int t = blockIdx.x*256 + threadIdx.x;
    int b = t / (P1*P1);
    int r = t % (P1*P1);
    int oy = r / P1, ox = r % P1;
    const unsigned short* ab = a1b + (size_t)b * (P1*P1);

    int p[32];
#pragma unroll
    for (int co = 0; co < 32; ++co) p[co] = 0;
    int nv = 0;
    for (int ky = 0; ky < 5; ++ky) {
        int iy = oy + ky - 2; if (iy < 0 || iy >= P1) continue;
        for (int kx = 0; kx < 5; ++kx) {
            int ix = ox + kx - 2; if (ix < 0 || ix >= P1) continue;
            ++nv;
            unsigned am = ab[iy*P1 + ix];
            int kk = ky*5 + kx;
#pragma unroll
            for (int co = 0; co < 32; ++co)
                p[co] += __popc(am ^ (unsigned)sw[co*25 + kk]);
        }
    }

    __shared__ double lsum[4][32], lsq[4][32];
    int wave = threadIdx.x >> 6, lane = threadIdx.x & 63;
#pragma unroll 1
    for (int co = 0; co < 32; ++co) {
        float yf = (float)(16*nv - 2*p[co]) + sb[co];
        double yd = (double)yf;
        double s = yd, q = yd*yd;
#pragma unroll
        for (int off = 32; off; off >>= 1) {
            s += __shfl_down(s, off);
            q += __shfl_down(q, off);
        }
        if (!lane) { lsum[wave][co] = s; lsq[wave][co] = q; }
    }
    __syncthreads();
    if (threadIdx.x < 32) {
        int co = threadIdx.x;
        partial2[(size_t)blockIdx.x*64 + co] =
            lsum[0][co] + lsum[1][co] + lsum[2][co] + lsum[3][co];
    } else if (threadIdx.x < 64) {
        int co = threadIdx.x - 32;
        partial2[(size_t)blockIdx.x*64 + 32 + co] =
            lsq[0][co] + lsq[1][co] + lsq[2][co] + lsq[3][co];
    }
}

__global__ __launch_bounds__(256) void k_finalize2(const double* __restrict__ part,
                                                   const float* __restrict__ g,
                                                   const float* __restrict__ be,
                                                   double* __restrict__ thr,
                                                   int* __restrict__ mode) {
    int c = blockIdx.x;
    double s = 0, q = 0;
    for (int i = threadIdx.x; i < NBLK2; i += 256) {
        s += part[(size_t)i*64 + c];
        q += part[(size_t)i*64 + 32 + c];
    }
    __shared__ double ls[256], lq[256];
    ls[threadIdx.x] = s; lq[threadIdx.x] = q;
    __syncthreads();
    for (int st = 128; st > 0; st >>= 1) {
        if (threadIdx.x < st) {
            ls[threadIdx.x] += ls[threadIdx.x + st];
            lq[threadIdx.x] += lq[threadIdx.x + st];
        }
        __syncthreads();
    }
    if (threadIdx.x == 0) {
        double N = (double)(BATCH * P1 * P1);
        double m = ls[0] / N;
        double var = lq[0] / N - m*m;
        double gamma = (double)g[c], beta = (double)be[c];
        double sc = gamma / sqrt(var + 1e-5);
        int md; double tt = 0.0;
        if (sc > 0)      { md = 0; tt = m - beta / sc; }
        else if (sc < 0) { md = 1; tt = m - beta / sc; }
        else             { md = (beta >= 0) ? 2 : 3; }
        thr[c] = tt; mode[c] = md;
    }
}

// ---------------------------------------------------------------------------
// Pass 2b: recompute conv2, 2x2 maxpool (+bias f32), sign -> a2 bytes
// a2 layout: [b][c*49 + py*7 + px]  (matches reference reshape)
// ---------------------------------------------------------------------------
__global__ __launch_bounds__(256) void k_a2(const unsigned short* __restrict__ a1b,
                                            const unsigned short* __restrict__ w2b,
                                            const float* __restrict__ b2,
                                            const double* __restrict__ thr,
                                            const int* __restrict__ mode,
                                            char* __restrict__ a2) {
    __shared__ unsigned short sw[800];
    __shared__ float sb[32];
    for (int i = threadIdx.x; i < 800; i += 256) sw[i] = w2b[i];
    if (threadIdx.x < 32) sb[threadIdx.x] = b2[threadIdx.x];
    __syncthreads();

    int t = blockIdx.x*256 + threadIdx.x;
    int b = t / (P2*P2);
    int r = t % (P2*P2);
    int py = r / P2, px = r % P2;
    const unsigned short* ab = a1b + (size_t)b * (P1*P1);

    int mx[32], mn[32];
#pragma unroll
    for (int co = 0; co < 32; ++co) { mx[co] = -1000000; mn[co] = 1000000; }

#pragma unroll 1
    for (int sp = 0; sp < 4; ++sp) {
        int sy = sp >> 1, sx = sp & 1;
        int oy = 2*py + sy, ox = 2*px + sx;
        int p[32];
#pragma unroll
        for (int co = 0; co < 32; ++co) p[co] = 0;
        int nv = 0;
        for (int ky = 0; ky < 5; ++ky) {
            int iy = oy + ky - 2; if (iy < 0 || iy >= P1) continue;
            for (int kx = 0; kx < 5; ++kx) {
                int ix = ox + kx - 2; if (ix < 0 || ix >= P1) continue;
                ++nv;
                unsigned am = ab[iy*P1 + ix];
                int kk = ky*5 + kx;
#pragma unroll
                for (int co = 0; co < 32; ++co)
                    p[co] += __popc(am ^ (unsigned)sw[co*25 + kk]);
            }
        }
#pragma unroll
        for (int co = 0; co < 32; ++co) {
            int y = 16*nv - 2*p[co];
            mx[co] = (y > mx[co]) ? y : mx[co];
            mn[co] = (y < mn[co]) ? y : mn[co];
        }
    }

#pragma unroll 1
    for (int co = 0; co < 32; ++co) {
        int md = mode[co]; double tt = thr[co];
        float ymx = (float)mx[co] + sb[co];
        float ymn = (float)mn[co] + sb[co];
        bool plus = (md == 0) ? ((double)ymx >= tt)
                  : (md == 1) ? ((double)ymn <= tt)
                  : (md == 2);
        a2[(size_t)b*1568 + co*49 + py*7 + px] = plus ? (char)1 : (char)-1;
    }
}

// ---------------------------------------------------------------------------
// FC: out[b][j] = popcount-dot(a2 row, sign(fc_w) row) + fc_b
// (exact: all f32 partial sums are small integers)
// ---------------------------------------------------------------------------
__global__ __launch_bounds__(256) void k_fc(const char* __restrict__ a2,
                                            const unsigned* __restrict__ fcp,
                                            const float* __restrict__ fcb,
                                            float* __restrict__ out) {
    int t = blockIdx.x*256 + threadIdx.x;  // < 81920
    int b = t / 10, j = t % 10;
    const unsigned* ar = (const unsigned*)(a2 + (size_t)b*1568);
    const unsigned* wr = fcp + j*392;
    int p = 0;
    for (int g = 0; g < 392; ++g)
        p += __popc((ar[g] ^ wr[g]) & 0x02020202u);
    out[t] = (float)(1568 - 2*p) + fcb[j];
}

// ---------------------------------------------------------------------------
extern "C" void kernel_launch(void* const* d_in, const int* in_sizes, int n_in,
                              void* d_out, int out_size, void* d_ws, size_t ws_size,
                              hipStream_t stream) {
    const float* x    = (const float*)d_in[0];
    const float* w1   = (const float*)d_in[1];
    const float* b1   = (const float*)d_in[2];
    const float* bn1g = (const float*)d_in[3];
    const float* bn1b = (const float*)d_in[4];
    const float* w2   = (const float*)d_in[5];
    const float* b2   = (const float*)d_in[6];
    const float* bn2g = (const float*)d_in[7];
    const float* bn2b = (const float*)d_in[8];
    const float* fcw  = (const float*)d_in[9];
    const float* fcb  = (const float*)d_in[10];
    float* out = (float*)d_out;

    char* ws = (char*)d_ws;
    size_t cur = 0;
    auto alloc = [&](size_t sz) {
        size_t o = cur;
        cur += (sz + 255) & ~(size_t)255;
        return o;
    };
    float*          w1f      = (float*)(ws + alloc(400 * 4));
    unsigned short* w2b      = (unsigned short*)(ws + alloc(800 * 2));
    unsigned*       fcp      = (unsigned*)(ws + alloc(3920 * 4));
    double*         thr1     = (double*)(ws + alloc(16 * 8));
    int*            mode1    = (int*)(ws + alloc(16 * 4));
    double*         thr2     = (double*)(ws + alloc(32 * 8));
    int*            mode2    = (int*)(ws + alloc(32 * 4));
    double*         partial1 = (double*)(ws + alloc((size_t)NBLK1 * 32 * 8));
    double*         partial2 = (double*)(ws + alloc((size_t)NBLK2 * 64 * 8));
    unsigned short* a1b      = (unsigned short*)(ws + alloc((size_t)BATCH * P1 * P1 * 2));
    char*           a2       = (char*)(ws + alloc((size_t)BATCH * 1568));

    k_prep<<<1, 256, 0, stream>>>(w1, w2, fcw, w1f, w2b, fcp);
    k_conv1_stats<<<NBLK1, 256, 0, stream>>>(x, w1f, b1, partial1);
    k_finalize1<<<16, 256, 0, stream>>>(partial1, bn1g, bn1b, thr1, mode1);
    k_a1<<<NBLK2, 256, 0, stream>>>(x, w1f, b1, thr1, mode1, a1b);
    k_conv2_stats<<<NBLK2, 256, 0, stream>>>(a1b, w2b, b2, partial2);
    k_finalize2<<<32, 256, 0, stream>>>(partial2, bn2g, bn2b, thr2, mode2);
    k_a2<<<1568, 256, 0, stream>>>(a1b, w2b, b2, thr2, mode2, a2);
    k_fc<<<320, 256, 0, stream>>>(a2, fcp, fcb, out);
}

// Round 3
// 343.634 us; speedup vs baseline: 3.6899x; 3.6899x over previous
//
#include <hip/hip_runtime.h>
#include <stdint.h>

#define BATCH 8192
#define H1 28
#define W1 28
#define C1 16
#define P1 14
#define C2 32
#define P2 7

#define NPIX1  (BATCH*H1*W1)    // 6,422,528
#define NPOOL1 (BATCH*P1*P1)    // 1,605,632
#define NPOOL2 (BATCH*P2*P2)    // 401,408

#define NBLK1 25088             // path B conv1 blocks
#define NBLK2 6272              // path B blocks / NPOOL1/256

#define CM1_BLOCKS 1568
#define CM1_ITERS  4            // 1568*256*4 = NPOOL1
#define CM2_BLOCKS 3136         // NPOOL2*2/256

typedef float f32x2 __attribute__((ext_vector_type(2)));

// ---------------------------------------------------------------------------
// Weight prep: binarized weight tables for both paths.
//  w1f : float ±1 [16][25] (path B)        w1s : 25-bit sign masks [16] (path A)
//  w2b : u16 channel masks [32][25]        w2p : packed tap-pairs [32][13]
//  fcp : packed sign bytes [10][392]       selb: {g1<0 bits, g2<0 bits}
// ---------------------------------------------------------------------------
__global__ __launch_bounds__(256) void k_prep(const float* __restrict__ w1,
                                              const float* __restrict__ w2,
                                              const float* __restrict__ fcw,
                                              const float* __restrict__ g1,
                                              const float* __restrict__ g2,
                                              float* __restrict__ w1f,
                                              unsigned* __restrict__ w1s,
                                              unsigned short* __restrict__ w2b,
                                              unsigned* __restrict__ w2p,
                                              unsigned* __restrict__ fcp,
                                              unsigned* __restrict__ selb) {
    for (int i = threadIdx.x; i < 400; i += blockDim.x)
        w1f[i] = (w1[i] >= 0.f) ? 1.f : -1.f;
    for (int c = threadIdx.x; c < 16; c += blockDim.x) {
        unsigned sb = 0;
        for (int i = 0; i < 25; ++i)
            if (w1[c*25 + i] < 0.f) sb |= 1u << i;
        w1s[c] = sb;
    }
    for (int i = threadIdx.x; i < 800; i += blockDim.x) {
        int co = i / 25, kk = i % 25;
        unsigned m = 0;
        for (int ci = 0; ci < 16; ++ci)
            if (w2[co*400 + ci*25 + kk] >= 0.f) m |= 1u << ci;
        w2b[i] = (unsigned short)m;
    }
    for (int i = threadIdx.x; i < 32*13; i += blockDim.x) {
        int co = i / 13, j = i % 13;
        int k1, k2;
        if (j < 10)      { k1 = (j/2)*5 + (j&1)*2; k2 = k1 + 1; }
        else if (j == 10){ k1 = 4;  k2 = 9;  }
        else if (j == 11){ k1 = 14; k2 = 19; }
        else             { k1 = 24; k2 = -1; }
        unsigned lo = 0, hi = 0;
        for (int ci = 0; ci < 16; ++ci) {
            if (w2[co*400 + ci*25 + k1] >= 0.f) lo |= 1u << ci;
            if (k2 >= 0 && w2[co*400 + ci*25 + k2] >= 0.f) hi |= 1u << ci;
        }
        w2p[i] = lo | (hi << 16);
    }
    for (int i = threadIdx.x; i < 3920; i += blockDim.x) {
        int j = i / 392, g = i % 392;
        unsigned v = 0;
        for (int by = 0; by < 4; ++by) {
            int k = g*4 + by;
            unsigned char s = (fcw[j*1568 + k] >= 0.f) ? 0x01 : 0xFF;
            v |= ((unsigned)s) << (8*by);
        }
        fcp[i] = v;
    }
    if (threadIdx.x == 0) {
        unsigned s1 = 0, s2 = 0;
        for (int c = 0; c < 16; ++c) if (g1[c] < 0.f) s1 |= 1u << c;
        for (int c = 0; c < 32; ++c) if (g2[c] < 0.f) s2 |= 1u << c;
        selb[0] = s1; selb[1] = s2;
    }
}

// ---------------------------------------------------------------------------
// PATH A: conv1 once. Per thread: ITERS pooled positions; computes the 4 conv
// values (exact f32 chains, tap order 0..24, via ±1 sign-flip adds == fmaf),
// stores selected pooled extremum per channel, accumulates f64 stats in
// registers; ONE butterfly per thread at the end.
// ---------------------------------------------------------------------------
__global__ __launch_bounds__(256) void k_conv1_minmax(const float* __restrict__ x,
                                                      const unsigned* __restrict__ w1s,
                                                      const float* __restrict__ b1,
                                                      const unsigned* __restrict__ selb,
                                                      float* __restrict__ ext1,
                                                      double* __restrict__ partial1) {
    unsigned selbs = __builtin_amdgcn_readfirstlane(selb[0]);
    double s[16], q[16];
#pragma unroll
    for (int c = 0; c < 16; ++c) { s[c] = 0.0; q[c] = 0.0; }

#pragma unroll 1
    for (int it = 0; it < CM1_ITERS; ++it) {
        int t = blockIdx.x*(256*CM1_ITERS) + it*256 + threadIdx.x;
        int b = t / (P1*P1);
        int r = t % (P1*P1);
        int py = r / P1, px = r % P1;
        const float* xb = x + (size_t)b * (H1*W1);

        float xd[36];
#pragma unroll
        for (int dy = 0; dy < 6; ++dy) {
            int iy = 2*py + dy - 2;
#pragma unroll
            for (int dx = 0; dx < 6; ++dx) {
                int ix = 2*px + dx - 2;
                xd[dy*6 + dx] = (iy >= 0 && iy < H1 && ix >= 0 && ix < W1)
                              ? xb[iy*W1 + ix] : 0.f;
            }
        }

#pragma unroll
        for (int c = 0; c < 16; ++c) {
            unsigned sb = __builtin_amdgcn_readfirstlane(w1s[c]);
            f32x2 y01 = {0.f, 0.f}, y23 = {0.f, 0.f};
#pragma unroll
            for (int ky = 0; ky < 5; ++ky) {
#pragma unroll
                for (int kx = 0; kx < 5; ++kx) {
                    float m = __uint_as_float(0x3F800000u ^
                                (((sb >> (ky*5 + kx)) & 1u) << 31));
                    f32x2 x01 = { xd[ ky   *6 + kx], xd[ ky   *6 + kx + 1] };
                    f32x2 x23 = { xd[(ky+1)*6 + kx], xd[(ky+1)*6 + kx + 1] };
                    y01 = x01 * m + y01;   // exact: ±x add == fmaf(±1,x,·)
                    y23 = x23 * m + y23;
                }
            }
            float bbc = b1[c];
            float y0 = y01.x + bbc, y1 = y01.y + bbc;
            float y2 = y23.x + bbc, y3 = y23.y + bbc;
            float mx = fmaxf(fmaxf(y0, y1), fmaxf(y2, y3));
            float mn = fminf(fminf(y0, y1), fminf(y2, y3));
            ext1[(size_t)c*NPOOL1 + t] = ((selbs >> c) & 1u) ? mn : mx;
            double d0 = y0, d1 = y1, d2 = y2, d3 = y3;
            s[c] += (d0 + d1) + (d2 + d3);
            q[c] += (d0*d0 + d1*d1) + (d2*d2 + d3*d3);
        }
    }

    __shared__ double lsum[4][16], lsq[4][16];
    int wave = threadIdx.x >> 6, lane = threadIdx.x & 63;
#pragma unroll
    for (int c = 0; c < 16; ++c) {
        double ss = s[c], qq = q[c];
#pragma unroll
        for (int off = 32; off; off >>= 1) {
            ss += __shfl_down(ss, off);
            qq += __shfl_down(qq, off);
        }
        if (lane == 0) { lsum[wave][c] = ss; lsq[wave][c] = qq; }
    }
    __syncthreads();
    if (threadIdx.x < 16) {
        int c = threadIdx.x;
        partial1[(size_t)blockIdx.x*32 + c] =
            lsum[0][c] + lsum[1][c] + lsum[2][c] + lsum[3][c];
    } else if (threadIdx.x < 32) {
        int c = threadIdx.x - 16;
        partial1[(size_t)blockIdx.x*32 + 16 + c] =
            lsq[0][c] + lsq[1][c] + lsq[2][c] + lsq[3][c];
    }
}

// finalize1: reduce partials, per-channel threshold + mode (shared by paths)
__global__ __launch_bounds__(256) void k_finalize1(const double* __restrict__ part,
                                                   int nblk,
                                                   const float* __restrict__ g,
                                                   const float* __restrict__ be,
                                                   double* __restrict__ thr,
                                                   int* __restrict__ mode) {
    int c = blockIdx.x;
    double s = 0, q = 0;
    for (int i = threadIdx.x; i < nblk; i += 256) {
        s += part[(size_t)i*32 + c];
        q += part[(size_t)i*32 + 16 + c];
    }
    __shared__ double ls[256], lq[256];
    ls[threadIdx.x] = s; lq[threadIdx.x] = q;
    __syncthreads();
    for (int st = 128; st > 0; st >>= 1) {
        if (threadIdx.x < st) {
            ls[threadIdx.x] += ls[threadIdx.x + st];
            lq[threadIdx.x] += lq[threadIdx.x + st];
        }
        __syncthreads();
    }
    if (threadIdx.x == 0) {
        double N = (double)NPIX1;
        double m = ls[0] / N;
        double var = lq[0] / N - m*m;
        double gamma = (double)g[c], beta = (double)be[c];
        double sc = gamma / sqrt(var + 1e-5);
        int md; double tt = 0.0;
        if (sc > 0)      { md = 0; tt = m - beta / sc; }
        else if (sc < 0) { md = 1; tt = m - beta / sc; }
        else             { md = (beta >= 0) ? 2 : 3; }
        thr[c] = tt; mode[c] = md;
    }
}

// PATH A: signs from stored extrema (memory-bound)
__global__ __launch_bounds__(256) void k_sign1(const float* __restrict__ ext1,
                                               const double* __restrict__ thr,
                                               const int* __restrict__ mode,
                                               unsigned short* __restrict__ a1b) {
    int t = blockIdx.x*256 + threadIdx.x;
    unsigned bits = 0;
#pragma unroll
    for (int c = 0; c < 16; ++c) {
        float v = ext1[(size_t)c*NPOOL1 + t];
        int md = mode[c]; double tt = thr[c];
        bool plus = (md == 0) ? ((double)v >= tt)
                  : (md == 1) ? ((double)v <= tt)
                  : (md == 2);
        bits |= (plus ? 1u : 0u) << c;
    }
    a1b[t] = (unsigned short)bits;
}

// ---------------------------------------------------------------------------
// PATH A: conv2 once via packed XNOR-popcount (2 taps/dword, 13 popcs/channel).
// Thread pair (half=idx&1) splits 32 channels. Stores selected int16 extremum,
// accumulates int stats, parity-preserving butterfly (offsets 32..2).
// ---------------------------------------------------------------------------
__global__ __launch_bounds__(256) void k_conv2_minmax(const unsigned short* __restrict__ a1b,
                                                      const unsigned* __restrict__ w2p,
                                                      const unsigned* __restrict__ selb,
                                                      short* __restrict__ ext2,
                                                      int* __restrict__ partial2) {
    __shared__ unsigned swp[32*13];
    for (int i = threadIdx.x; i < 416; i += 256) swp[i] = w2p[i];
    __syncthreads();

    int idx = blockIdx.x*256 + threadIdx.x;     // < NPOOL2*2
    int t = idx >> 1;
    int half = idx & 1;
    int half16 = half << 4;
    unsigned selbs = __builtin_amdgcn_readfirstlane(selb[1]);

    int b = t / (P2*P2);
    int r = t % (P2*P2);
    int qy = r / P2, qx = r % P2;
    const unsigned short* ab = a1b + (size_t)b * (P1*P1);

    int rv[6], cv[6];
#pragma unroll
    for (int w = 0; w < 6; ++w) {
        int iy = 2*qy + w - 2; rv[w] = (iy >= 0 && iy < P1) ? 1 : 0;
        int ix = 2*qx + w - 2; cv[w] = (ix >= 0 && ix < P1) ? 1 : 0;
    }
    unsigned am[36];
#pragma unroll
    for (int wy = 0; wy < 6; ++wy) {
#pragma unroll
        for (int wx = 0; wx < 6; ++wx) {
            int iy = 2*qy + wy - 2, ix = 2*qx + wx - 2;
            am[wy*6 + wx] = (rv[wy] && cv[wx]) ? (unsigned)ab[iy*P1 + ix] : 0u;
        }
    }

    int s[16], q[16], mx[16], mn[16];
#pragma unroll
    for (int c = 0; c < 16; ++c) { s[c]=0; q[c]=0; mx[c]=-1000000; mn[c]=1000000; }

#pragma unroll
    for (int sp = 0; sp < 4; ++sp) {
        const int sy = sp >> 1, sx = sp & 1;
        int nvr = rv[sy]+rv[sy+1]+rv[sy+2]+rv[sy+3]+rv[sy+4];
        int nvc = cv[sx]+cv[sx+1]+cv[sx+2]+cv[sx+3]+cv[sx+4];
        int nv16 = (nvr * nvc) << 4;

        unsigned ap[13], vm[13];
#pragma unroll
        for (int ky = 0; ky < 5; ++ky) {
            ap[ky*2+0] = am[(sy+ky)*6 + sx+0] | (am[(sy+ky)*6 + sx+1] << 16);
            vm[ky*2+0] = ((rv[sy+ky]&cv[sx+0]) ? 0x0000FFFFu : 0u)
                       | ((rv[sy+ky]&cv[sx+1]) ? 0xFFFF0000u : 0u);
            ap[ky*2+1] = am[(sy+ky)*6 + sx+2] | (am[(sy+ky)*6 + sx+3] << 16);
            vm[ky*2+1] = ((rv[sy+ky]&cv[sx+2]) ? 0x0000FFFFu : 0u)
                       | ((rv[sy+ky]&cv[sx+3]) ? 0xFFFF0000u : 0u);
        }
        ap[10] = am[(sy+0)*6 + sx+4] | (am[(sy+1)*6 + sx+4] << 16);
        vm[10] = ((rv[sy+0]&cv[sx+4]) ? 0x0000FFFFu : 0u)
               | ((rv[sy+1]&cv[sx+4]) ? 0xFFFF0000u : 0u);
        ap[11] = am[(sy+2)*6 + sx+4] | (am[(sy+3)*6 + sx+4] << 16);
        vm[11] = ((rv[sy+2]&cv[sx+4]) ? 0x0000FFFFu : 0u)
               | ((rv[sy+3]&cv[sx+4]) ? 0xFFFF0000u : 0u);
        ap[12] = am[(sy+4)*6 + sx+4];
        vm[12] = (rv[sy+4]&cv[sx+4]) ? 0x0000FFFFu : 0u;

#pragma unroll
        for (int cl = 0; cl < 16; ++cl) {
            const unsigned* wr = swp + (half16 + cl)*13;
            int p = 0;
#pragma unroll
            for (int j = 0; j < 13; ++j)
                p += __popc(ap[j] ^ (wr[j] & vm[j]));
            int y = nv16 - 2*p;
            s[cl] += y; q[cl] += y*y;
            mx[cl] = (y > mx[cl]) ? y : mx[cl];
            mn[cl] = (y < mn[cl]) ? y : mn[cl];
        }
    }

#pragma unroll
    for (int cl = 0; cl < 16; ++cl) {
        int co = half16 + cl;
        int sel = (selbs >> co) & 1;
        ext2[(size_t)co*NPOOL2 + t] = (short)(sel ? mn[cl] : mx[cl]);
    }

    __shared__ int lsum[4][32], lsq[4][32];
    int wave = threadIdx.x >> 6, lane = threadIdx.x & 63;
#pragma unroll
    for (int cl = 0; cl < 16; ++cl) {
        int ss = s[cl], qq = q[cl];
#pragma unroll
        for (int off = 32; off >= 2; off >>= 1) {   // parity-preserving
            ss += __shfl_down(ss, off);
            qq += __shfl_down(qq, off);
        }
        if (lane <= 1) {     // lane0: half0, lane1: half1
            lsum[wave][lane*16 + cl] = ss;
            lsq[wave][lane*16 + cl]  = qq;
        }
    }
    __syncthreads();
    if (threadIdx.x < 32) {
        int co = threadIdx.x;
        partial2[(size_t)blockIdx.x*64 + co] =
            lsum[0][co] + lsum[1][co] + lsum[2][co] + lsum[3][co];
    } else if (threadIdx.x < 64) {
        int co = threadIdx.x - 32;
        partial2[(size_t)blockIdx.x*64 + 32 + co] =
            lsq[0][co] + lsq[1][co] + lsq[2][co] + lsq[3][co];
    }
}

// PATH A finalize2 (int partials); thr on (y + bias) scale
__global__ __launch_bounds__(256) void k_finalize2i(const int* __restrict__ part,
                                                    int nblk,
                                                    const float* __restrict__ b2,
                                                    const float* __restrict__ g,
                                                    const float* __restrict__ be,
                                                    double* __restrict__ thr,
                                                    int* __restrict__ mode) {
    int c = blockIdx.x;
    long long s = 0, q = 0;
    for (int i = threadIdx.x; i < nblk; i += 256) {
        s += (long long)part[(size_t)i*64 + c];
        q += (long long)part[(size_t)i*64 + 32 + c];
    }
    __shared__ long long ls[256], lq[256];
    ls[threadIdx.x] = s; lq[threadIdx.x] = q;
    __syncthreads();
    for (int st = 128; st > 0; st >>= 1) {
        if (threadIdx.x < st) {
            ls[threadIdx.x] += ls[threadIdx.x + st];
            lq[threadIdx.x] += lq[threadIdx.x + st];
        }
        __syncthreads();
    }
    if (threadIdx.x == 0) {
        double N = (double)(BATCH * P1 * P1);
        double my = (double)ls[0] / N;
        double var = (double)lq[0] / N - my*my;   // bias-shift invariant
        double m = my + (double)b2[c];
        double gamma = (double)g[c], beta = (double)be[c];
        double sc = gamma / sqrt(var + 1e-5);
        int md; double tt = 0.0;
        if (sc > 0)      { md = 0; tt = m - beta / sc; }
        else if (sc < 0) { md = 1; tt = m - beta / sc; }
        else             { md = (beta >= 0) ? 2 : 3; }
        thr[c] = tt; mode[c] = md;
    }
}

// PATH A: stage-2 signs; emulate fl32(y + b2) exactly before f64 compare
__global__ __launch_bounds__(256) void k_sign2(const short* __restrict__ ext2,
                                               const float* __restrict__ b2,
                                               const double* __restrict__ thr,
                                               const int* __restrict__ mode,
                                               char* __restrict__ a2) {
    int t = blockIdx.x*256 + threadIdx.x;
    int b = t / (P2*P2);
    int r = t % (P2*P2);
#pragma unroll 1
    for (int co = 0; co < 32; ++co) {
        short v = ext2[(size_t)co*NPOOL2 + t];
        float yf = (float)v + b2[co];
        int md = mode[co]; double tt = thr[co];
        bool plus = (md == 0) ? ((double)yf >= tt)
                  : (md == 1) ? ((double)yf <= tt)
                  : (md == 2);
        a2[(size_t)b*1568 + co*49 + r] = plus ? (char)1 : (char)-1;
    }
}

// ---------------------------------------------------------------------------
// PATH B (fallback, proven round-2 kernels)
// ---------------------------------------------------------------------------
__global__ __launch_bounds__(256) void k_conv1_stats(const float* __restrict__ x,
                                                     const float* __restrict__ w1f,
                                                     const float* __restrict__ b1,
                                                     double* __restrict__ partial1) {
    int t = blockIdx.x*256 + threadIdx.x;
    int b = t / (H1*W1);
    int r = t % (H1*W1);
    int oy = r / W1, ox = r % W1;
    const float* xb = x + (size_t)b * (H1*W1);
    float xd[25];
#pragma unroll
    for (int ky = 0; ky < 5; ++ky) {
        int iy = oy + ky - 2;
#pragma unroll
        for (int kx = 0; kx < 5; ++kx) {
            int ix = ox + kx - 2;
            xd[ky*5 + kx] = (iy >= 0 && iy < H1 && ix >= 0 && ix < W1) ? xb[iy*W1 + ix] : 0.f;
        }
    }
    __shared__ double lsum[4][C1], lsq[4][C1];
    int wave = threadIdx.x >> 6, lane = threadIdx.x & 63;
#pragma unroll 1
    for (int c = 0; c < C1; ++c) {
        float y = 0.f;
#pragma unroll
        for (int i = 0; i < 25; ++i) y = fmaf(w1f[c*25 + i], xd[i], y);
        y = y + b1[c];
        double yd = (double)y;
        double s = yd, q = yd*yd;
#pragma unroll
        for (int off = 32; off; off >>= 1) {
            s += __shfl_down(s, off);
            q += __shfl_down(q, off);
        }
        if (lane == 0) { lsum[wave][c] = s; lsq[wave][c] = q; }
    }
    __syncthreads();
    if (threadIdx.x < C1) {
        int c = threadIdx.x;
        partial1[(size_t)blockIdx.x*32 + c] = lsum[0][c]+lsum[1][c]+lsum[2][c]+lsum[3][c];
    } else if (threadIdx.x < 2*C1) {
        int c = threadIdx.x - C1;
        partial1[(size_t)blockIdx.x*32 + 16 + c] = lsq[0][c]+lsq[1][c]+lsq[2][c]+lsq[3][c];
    }
}

__global__ __launch_bounds__(256) void k_a1(const float* __restrict__ x,
                                            const float* __restrict__ w1f,
                                            const float* __restrict__ b1,
                                            const double* __restrict__ thr,
                                            const int* __restrict__ mode,
                                            unsigned short* __restrict__ a1b) {
    int t = blockIdx.x*256 + threadIdx.x;
    int b = t / (P1*P1);
    int r = t % (P1*P1);
    int py = r / P1, px = r % P1;
    const float* xb = x + (size_t)b * (H1*W1);
    float xd[36];
#pragma unroll
    for (int dy = 0; dy < 6; ++dy) {
        int iy = 2*py + dy - 2;
#pragma unroll
        for (int dx = 0; dx < 6; ++dx) {
            int ix = 2*px + dx - 2;
            xd[dy*6 + dx] = (iy >= 0 && iy < H1 && ix >= 0 && ix < W1) ? xb[iy*W1 + ix] : 0.f;
        }
    }
    unsigned maskbits = 0;
#pragma unroll 1
    for (int c = 0; c < C1; ++c) {
        float y0=0.f, y1=0.f, y2=0.f, y3=0.f;
#pragma unroll
        for (int ky = 0; ky < 5; ++ky)
#pragma unroll
            for (int kx = 0; kx < 5; ++kx) {
                float w = w1f[c*25 + ky*5 + kx];
                y0 = fmaf(w, xd[ ky   *6 + kx    ], y0);
                y1 = fmaf(w, xd[ ky   *6 + kx + 1], y1);
                y2 = fmaf(w, xd[(ky+1)*6 + kx    ], y2);
                y3 = fmaf(w, xd[(ky+1)*6 + kx + 1], y3);
            }
        float bb = b1[c];
        y0+=bb; y1+=bb; y2+=bb; y3+=bb;
        float mx = fmaxf(fmaxf(y0,y1), fmaxf(y2,y3));
        float mn = fminf(fminf(y0,y1), fminf(y2,y3));
        int md = mode[c]; double tt = thr[c];
        bool plus = (md == 0) ? ((double)mx >= tt)
                  : (md == 1) ? ((double)mn <= tt)
                  : (md == 2);
        maskbits |= (plus ? 1u : 0u) << c;
    }
    a1b[t] = (unsigned short)maskbits;
}

__global__ __launch_bounds__(256) void k_conv2_stats(const unsigned short* __restrict__ a1b,
                                                     const unsigned short* __restrict__ w2b,
                                                     const float* __restrict__ b2,
                                                     double* __restrict__ partial2) {
    __shared__ unsigned short sw[800];
    __shared__ float sb[32];
    for (int i = threadIdx.x; i < 800; i += 256) sw[i] = w2b[i];
    if (threadIdx.x < 32) sb[threadIdx.x] = b2[threadIdx.x];
    __syncthreads();
    int t = blockIdx.x*256 + threadIdx.x;
    int b = t / (P1*P1);
    int r = t % (P1*P1);
    int oy = r / P1, ox = r % P1;
    const unsigned short* ab = a1b + (size_t)b * (P1*P1);
    int p[32];
#pragma unroll
    for (int co = 0; co < 32; ++co) p[co] = 0;
    int nv = 0;
    for (int ky = 0; ky < 5; ++ky) {
        int iy = oy + ky - 2; if (iy < 0 || iy >= P1) continue;
        for (int kx = 0; kx < 5; ++kx) {
            int ix = ox + kx - 2; if (ix < 0 || ix >= P1) continue;
            ++nv;
            unsigned am = ab[iy*P1 + ix];
            int kk = ky*5 + kx;
#pragma unroll
            for (int co = 0; co < 32; ++co)
                p[co] += __popc(am ^ (unsigned)sw[co*25 + kk]);
        }
    }
    __shared__ double lsum[4][32], lsq[4][32];
    int wave = threadIdx.x >> 6, lane = threadIdx.x & 63;
#pragma unroll 1
    for (int co = 0; co < 32; ++co) {
        float yf = (float)(16*nv - 2*p[co]) + sb[co];
        double yd = (double)yf;
        double s = yd, q = yd*yd;
#pragma unroll
        for (int off = 32; off; off >>= 1) {
            s += __shfl_down(s, off);
            q += __shfl_down(q, off);
        }
        if (!lane) { lsum[wave][co] = s; lsq[wave][co] = q; }
    }
    __syncthreads();
    if (threadIdx.x < 32) {
        int co = threadIdx.x;
        partial2[(size_t)blockIdx.x*64 + co] = lsum[0][co]+lsum[1][co]+lsum[2][co]+lsum[3][co];
    } else if (threadIdx.x < 64) {
        int co = threadIdx.x - 32;
        partial2[(size_t)blockIdx.x*64 + 32 + co] = lsq[0][co]+lsq[1][co]+lsq[2][co]+lsq[3][co];
    }
}

__global__ __launch_bounds__(256) void k_finalize2d(const double* __restrict__ part,
                                                    int nblk,
                                                    const float* __restrict__ g,
                                                    const float* __restrict__ be,
                                                    double* __restrict__ thr,
                                                    int* __restrict__ mode) {
    int c = blockIdx.x;
    double s = 0, q = 0;
    for (int i = threadIdx.x; i < nblk; i += 256) {
        s += part[(size_t)i*64 + c];
        q += part[(size_t)i*64 + 32 + c];
    }
    __shared__ double ls[256], lq[256];
    ls[threadIdx.x] = s; lq[threadIdx.x] = q;
    __syncthreads();
    for (int st = 128; st > 0; st >>= 1) {
        if (threadIdx.x < st) {
            ls[threadIdx.x] += ls[threadIdx.x + st];
            lq[threadIdx.x] += lq[threadIdx.x + st];
        }
        __syncthreads();
    }
    if (threadIdx.x == 0) {
        double N = (double)(BATCH * P1 * P1);
        double m = ls[0] / N;
        double var = lq[0] / N - m*m;
        double gamma = (double)g[c], beta = (double)be[c];
        double sc = gamma / sqrt(var + 1e-5);
        int md; double tt = 0.0;
        if (sc > 0)      { md = 0; tt = m - beta / sc; }
        else if (sc < 0) { md = 1; tt = m - beta / sc; }
        else             { md = (beta >= 0) ? 2 : 3; }
        thr[c] = tt; mode[c] = md;
    }
}

__global__ __launch_bounds__(256) void k_a2(const unsigned short* __restrict__ a1b,
                                            const unsigned short* __restrict__ w2b,
                                            const float* __restrict__ b2,
                                            const double* __restrict__ thr,
                                            const int* __restrict__ mode,
                                            char* __restrict__ a2) {
    __shared__ unsigned short sw[800];
    __shared__ float sb[32];
    for (int i = threadIdx.x; i < 800; i += 256) sw[i] = w2b[i];
    if (threadIdx.x < 32) sb[threadIdx.x] = b2[threadIdx.x];
    __syncthreads();
    int t = blockIdx.x*256 + threadIdx.x;
    int b = t / (P2*P2);
    int r = t % (P2*P2);
    int py = r / P2, px = r % P2;
    const unsigned short* ab = a1b + (size_t)b * (P1*P1);
    int mx[32], mn[32];
#pragma unroll
    for (int co = 0; co < 32; ++co) { mx[co] = -1000000; mn[co] = 1000000; }
#pragma unroll 1
    for (int sp = 0; sp < 4; ++sp) {
        int sy = sp >> 1, sx = sp & 1;
        int oy = 2*py + sy, ox = 2*px + sx;
        int p[32];
#pragma unroll
        for (int co = 0; co < 32; ++co) p[co] = 0;
        int nv = 0;
        for (int ky = 0; ky < 5; ++ky) {
            int iy = oy + ky - 2; if (iy < 0 || iy >= P1) continue;
            for (int kx = 0; kx < 5; ++kx) {
                int ix = ox + kx - 2; if (ix < 0 || ix >= P1) continue;
                ++nv;
                unsigned am = ab[iy*P1 + ix];
                int kk = ky*5 + kx;
#pragma unroll
                for (int co = 0; co < 32; ++co)
                    p[co] += __popc(am ^ (unsigned)sw[co*25 + kk]);
            }
        }
#pragma unroll
        for (int co = 0; co < 32; ++co) {
            int y = 16*nv - 2*p[co];
            mx[co] = (y > mx[co]) ? y : mx[co];
            mn[co] = (y < mn[co]) ? y : mn[co];
        }
    }
#pragma unroll 1
    for (int co = 0; co < 32; ++co) {
        int md = mode[co]; double tt = thr[co];
        float ymx = (float)mx[co] + sb[co];
        float ymn = (float)mn[co] + sb[co];
        bool plus = (md == 0) ? ((double)ymx >= tt)
                  : (md == 1) ? ((double)ymn <= tt)
                  : (md == 2);
        a2[(size_t)b*1568 + co*49 + py*7 + px] = plus ? (char)1 : (char)-1;
    }
}

// FC (shared): popcount dot over ±1 bytes
__global__ __launch_bounds__(256) void k_fc(const char* __restrict__ a2,
                                            const unsigned* __restrict__ fcp,
                                            const float* __restrict__ fcb,
                                            float* __restrict__ out) {
    int t = blockIdx.x*256 + threadIdx.x;  // < 81920
    int b = t / 10, j = t % 10;
    const unsigned* ar = (const unsigned*)(a2 + (size_t)b*1568);
    const unsigned* wr = fcp + j*392;
    int p = 0;
    for (int g = 0; g < 392; ++g)
        p += __popc((ar[g] ^ wr[g]) & 0x02020202u);
    out[t] = (float)(1568 - 2*p) + fcb[j];
}

// ---------------------------------------------------------------------------
extern "C" void kernel_launch(void* const* d_in, const int* in_sizes, int n_in,
                              void* d_out, int out_size, void* d_ws, size_t ws_size,
                              hipStream_t stream) {
    const float* x    = (const float*)d_in[0];
    const float* w1   = (const float*)d_in[1];
    const float* b1   = (const float*)d_in[2];
    const float* bn1g = (const float*)d_in[3];
    const float* bn1b = (const float*)d_in[4];
    const float* w2   = (const float*)d_in[5];
    const float* b2   = (const float*)d_in[6];
    const float* bn2g = (const float*)d_in[7];
    const float* bn2b = (const float*)d_in[8];
    const float* fcw  = (const float*)d_in[9];
    const float* fcb  = (const float*)d_in[10];
    float* out = (float*)d_out;

    char* ws = (char*)d_ws;

    // ---- common small tables ----
    size_t cur = 0;
    auto alloc = [&](size_t sz) {
        size_t o = cur;
        cur += (sz + 255) & ~(size_t)255;
        return o;
    };
    float*          w1f   = (float*)(ws + alloc(400 * 4));
    unsigned*       w1s   = (unsigned*)(ws + alloc(16 * 4));
    unsigned short* w2b   = (unsigned short*)(ws + alloc(800 * 2));
    unsigned*       w2p   = (unsigned*)(ws + alloc(416 * 4));
    unsigned*       fcp   = (unsigned*)(ws + alloc(3920 * 4));
    unsigned*       selb  = (unsigned*)(ws + alloc(2 * 4));
    double*         thr1  = (double*)(ws + alloc(16 * 8));
    int*            mode1 = (int*)(ws + alloc(16 * 4));
    double*         thr2  = (double*)(ws + alloc(32 * 8));
    int*            mode2 = (int*)(ws + alloc(32 * 4));
    unsigned short* a1b   = (unsigned short*)(ws + alloc((size_t)NPOOL1 * 2));
    char*           a2    = (char*)(ws + alloc((size_t)BATCH * 1568));
    size_t common_end = cur;

    // ---- path A layout ----
    size_t curA = common_end;
    auto allocA = [&](size_t sz) {
        size_t o = curA;
        curA += (sz + 255) & ~(size_t)255;
        return o;
    };
    double* partial1A = (double*)(ws + allocA((size_t)CM1_BLOCKS * 32 * 8));
    int*    partial2A = (int*)(ws + allocA((size_t)CM2_BLOCKS * 64 * 4));
    float*  ext1      = (float*)(ws + allocA((size_t)C1 * NPOOL1 * 4));
    short*  ext2      = (short*)(ws + allocA((size_t)C2 * NPOOL2 * 2));
    bool pathA = (curA <= ws_size);

    k_prep<<<1, 256, 0, stream>>>(w1, w2, fcw, bn1g, bn2g,
                                  w1f, w1s, w2b, w2p, fcp, selb);

    if (pathA) {
        k_conv1_minmax<<<CM1_BLOCKS, 256, 0, stream>>>(x, w1s, b1, selb, ext1, partial1A);
        k_finalize1<<<16, 256, 0, stream>>>(partial1A, CM1_BLOCKS, bn1g, bn1b, thr1, mode1);
        k_sign1<<<NPOOL1/256, 256, 0, stream>>>(ext1, thr1, mode1, a1b);
        k_conv2_minmax<<<CM2_BLOCKS, 256, 0, stream>>>(a1b, w2p, selb, ext2, partial2A);
        k_finalize2i<<<32, 256, 0, stream>>>(partial2A, CM2_BLOCKS, b2, bn2g, bn2b, thr2, mode2);
        k_sign2<<<NPOOL2/256, 256, 0, stream>>>(ext2, b2, thr2, mode2, a2);
    } else {
        // ---- path B layout (round-2 fallback) ----
        size_t curB = common_end;
        auto allocB = [&](size_t sz) {
            size_t o = curB;
            curB += (sz + 255) & ~(size_t)255;
            return o;
        };
        double* partial1B = (double*)(ws + allocB((size_t)NBLK1 * 32 * 8));
        double* partial2B = (double*)(ws + allocB((size_t)NBLK2 * 64 * 8));
        k_conv1_stats<<<NBLK1, 256, 0, stream>>>(x, w1f, b1, partial1B);
        k_finalize1<<<16, 256, 0, stream>>>(partial1B, NBLK1, bn1g, bn1b, thr1, mode1);
        k_a1<<<NBLK2, 256, 0, stream>>>(x, w1f, b1, thr1, mode1, a1b);
        k_conv2_stats<<<NBLK2, 256, 0, stream>>>(a1b, w2b, b2, partial2B);
        k_finalize2d<<<32, 256, 0, stream>>>(partial2B, NBLK2, bn2g, bn2b, thr2, mode2);
        k_a2<<<1568, 256, 0, stream>>>(a1b, w2b, b2, thr2, mode2, a2);
    }
    k_fc<<<320, 256, 0, stream>>>(a2, fcp, fcb, out);
}